// Round 8
// baseline (414.616 us; speedup 1.0000x reference)
//
#include <hip/hip_runtime.h>
#include <hip/hip_bf16.h>
#include <hip/hip_fp16.h>
#include <cstdint>
#include <cstddef>
#include <type_traits>

// Problem constants (from reference): N=50000, E=800000, IN=512, HID=256, MID=128, OUT=64
// NOTE: edge packing below assumes N < 65536 (src index fits 16 bits). N=50000 -> ok.
#define F_IN  512
#define F_HID 256
#define F_MID 128
#define F_OUT 64

typedef __attribute__((ext_vector_type(8))) short short8;   // 8 x bf16 (4 VGPRs)
typedef __attribute__((ext_vector_type(4))) float floatx4;  // MFMA accumulator

static __device__ __forceinline__ ushort f2b(float f) {
  union { float f; unsigned u; } v; v.f = f;
  unsigned r = v.u + 0x7fffu + ((v.u >> 16) & 1u);  // round-to-nearest-even
  return (ushort)(r >> 16);
}
// bf16 pair packed in a uint: low half / high half -> f32 (just bit shifts)
static __device__ __forceinline__ float blo(unsigned u) {
  union { unsigned x; float f; } v; v.x = u << 16; return v.f;
}
static __device__ __forceinline__ float bhi(unsigned u) {
  union { unsigned x; float f; } v; v.x = u & 0xffff0000u; return v.f;
}
// 8x f32 -> 8x bf16 via packed v_cvt_pk_bf16_f32 (RNE)
static __device__ __forceinline__ short8 cvt8(float4 lo, float4 hi) {
  union { __hip_bfloat162 h[4]; short8 s; } r;
  r.h[0] = __float22bfloat162_rn({lo.x, lo.y});
  r.h[1] = __float22bfloat162_rn({lo.z, lo.w});
  r.h[2] = __float22bfloat162_rn({hi.x, hi.y});
  r.h[3] = __float22bfloat162_rn({hi.z, hi.w});
  return r.s;
}

// async global->LDS DMA, 16B per lane. LDS dest must be WAVE-UNIFORM base; HW scatters
// lane i to base + i*16. Global src is per-lane. size must be a literal (16).
static __device__ __forceinline__ void gload_lds16(const void* gsrc, void* ldst) {
  __builtin_amdgcn_global_load_lds(
      (const __attribute__((address_space(1))) unsigned int*)gsrc,
      (__attribute__((address_space(3))) unsigned int*)ldst, 16, 0, 0);
}

// ---------------- CSR build ----------------

__global__ __launch_bounds__(256) void hist_kernel(const int* __restrict__ dst,
                                                   int* __restrict__ cnt, int e) {
  int i = blockIdx.x * 256 + threadIdx.x;
  if (i < e) atomicAdd(&cnt[dst[i]], 1);
}

// hierarchical scan: (1) per-block exclusive scan + partial; zeroes cnt for cursor reuse.
// Also emits dinv[i] = rsqrt(1+deg) (fused former dinv_kernel; saves a launch + N-pass).
__global__ __launch_bounds__(1024) void scan1_kernel(int* __restrict__ cnt,
                                                     int* __restrict__ rp,
                                                     int* __restrict__ part,
                                                     float* __restrict__ dinv, int n) {
  __shared__ int buf[1024];
  int tid = threadIdx.x;
  int i = blockIdx.x * 1024 + tid;
  int v = (i < n) ? cnt[i] : 0;
  buf[tid] = v;
  __syncthreads();
  for (int off = 1; off < 1024; off <<= 1) {
    int t = (tid >= off) ? buf[tid - off] : 0;
    __syncthreads();
    buf[tid] += t;
    __syncthreads();
  }
  if (i < n) {
    rp[i] = buf[tid] - v;
    cnt[i] = 0;
    dinv[i] = rsqrtf(1.0f + (float)v);  // deg includes self-loop
  }
  if (tid == 1023) part[blockIdx.x] = buf[1023];
}

// (2) scan of block partials (nb <= 1024), also writes rp[n] = total (== E)
__global__ __launch_bounds__(1024) void scan2_kernel(int* __restrict__ part,
                                                     int* __restrict__ rp, int nb, int n) {
  __shared__ int buf[1024];
  int tid = threadIdx.x;
  int v = (tid < nb) ? part[tid] : 0;
  buf[tid] = v;
  __syncthreads();
  for (int off = 1; off < 1024; off <<= 1) {
    int t = (tid >= off) ? buf[tid - off] : 0;
    __syncthreads();
    buf[tid] += t;
    __syncthreads();
  }
  if (tid < nb) part[tid] = buf[tid] - v;   // exclusive block offsets
  if (tid == nb - 1) rp[n] = buf[tid];      // total
}

// (3) add block offsets
__global__ __launch_bounds__(1024) void scan3_kernel(const int* __restrict__ part,
                                                     int* __restrict__ rp, int n) {
  int b = blockIdx.x;
  int i = b * 1024 + threadIdx.x;
  if (b > 0 && i < n) rp[i] += part[b];
}

// fill CSR adjacency; packs src (low 16 bits, requires N<65536) and the f16-encoded
// edge weight dinv[s]*dinv[d] (high 16 bits) into one uint. This removes the per-edge
// random dinv[s] gather (and its load->fma dependency chain) from BOTH agg passes.
__global__ __launch_bounds__(256) void fill_kernel(const int* __restrict__ src,
                                                   const int* __restrict__ dst,
                                                   const int* __restrict__ rp,
                                                   int* __restrict__ cur,
                                                   const float* __restrict__ dinv,
                                                   unsigned* __restrict__ edg, int e) {
  int i = blockIdx.x * 256 + threadIdx.x;
  if (i < e) {
    int s = src[i], d = dst[i];
    int p = rp[d] + atomicAdd(&cur[d], 1);
    float w = dinv[s] * dinv[d];
    edg[p] = ((unsigned)__half_as_ushort(__float2half_rn(w)) << 16) | (unsigned)s;
  }
}

// W (f32, [K][F]) -> WT (bf16, [F][K])
__global__ __launch_bounds__(256) void transpose_kernel(const float* __restrict__ W,
                                                        ushort* __restrict__ WT,
                                                        int K, int F) {
  int i = blockIdx.x * 256 + threadIdx.x;
  if (i < K * F) {
    int k = i / F, f = i - k * F;
    WT[(size_t)f * K + k] = f2b(W[i]);
  }
}

// ---------------- 64-row MFMA GEMM, BK=64, double-buffered ----------------
// C[M,F] = A[M,K]*B[K,F], BT bf16 [F][K]. Tile 64(M) x NT(N), BK=64, two LDS buffers,
// ONE barrier per K-iter. Round-4 diagnosis: __syncthreads' implicit vmcnt(0) drains the
// full DMA latency EVERY 32-K step (MfmaUtil 6.7%, all pipes idle, 39% occ). BK=64 halves
// the number of drains and doubles MFMA per drain window; LDS 48KB -> 3 blocks/CU, which
// equals the residency we measured anyway.
// LDS tiles have 128-B rows (= exactly 32 banks, so bank depends ONLY on the 16B slot):
// unswizzled fragment reads would use 4 slots -> 16 banks idle, 2x the 8-cycle floor.
// XOR swizzle stored[row][slot] = orig[row][slot ^ (row&7)] gives exactly 8 lanes/slot =
// uniform 8 dwords/bank = the floor. gload_lds writes linearly, so the SOURCE col is
// pre-swizzled per-lane (both-sides-or-neither); readers apply slot ^ (ml&7) (row&7 ==
// ml&7 for all fragment rows). The f32-A register path swizzles at ds_write instead.
// PAIRX (gemm1): remap the (gM64,2) grid so the two col-tile blocks that read the SAME
// A rows land 8 block-ids apart -> same XCD (id%8 round-robin) -> second read L2-hits.
// LSM=true fuses log_softmax into the epilogue via a [64][65] f32 LDS tile.
// OOB rows index-clamped on loads, guarded on stores.
template<int K, int NT, bool A_F32, bool OUT_F32, bool LSM, bool PAIRX>
__global__ __launch_bounds__(256) void gemm64db(const void* __restrict__ Av,
                                                const ushort* __restrict__ BT,
                                                const float* __restrict__ bias,
                                                void* __restrict__ Cv,
                                                int M, int F) {
  constexpr int NJ   = NT / 64;       // col fragments per wave
  constexpr int NCHB = NT / 32;       // 4KB gload chunks of B per K-step
  __shared__ ushort As[2][64 * 64];   // 2 x 8 KB
  __shared__ ushort Bs[2][NT * 64];   // 2 x (NT/8) KB
  const int tid = threadIdx.x, lane = tid & 63, wv = tid >> 6;
  const int q = lane >> 4, ml = lane & 15;

  int bx = blockIdx.x, by = blockIdx.y;
  if (PAIRX) {
    int id = bx + (int)gridDim.x * by;
    int lim = ((int)gridDim.x & ~7) * 2;
    if (id < lim) { int u = id >> 4, v = id & 15; bx = u * 8 + (v & 7); by = v >> 3; }
    else { int r = id - lim; bx = (lim >> 1) + (r >> 1); by = r & 1; }
  }
  const int bm = bx << 6, bn = by * NT;
  const int wn = wv * (NT / 4);

  const int srow = tid >> 3;                      // staging row 0..31 (two 32-row halves)
  const int slotSwz = (tid & 7) ^ (srow & 7);     // swizzled 16B slot
  const int scS = slotSwz << 3;                   // swizzled source col (elements)
  const int sc2 = (tid & 7) << 3;                 // plain col (f32-A reg path)

  const int ra0 = min(bm + srow, M - 1);
  const int ra1 = min(bm + 32 + srow, M - 1);
  const float*  a32_0 = (const float*)Av + (size_t)ra0 * K + sc2;
  const float*  a32_1 = (const float*)Av + (size_t)ra1 * K + sc2;
  const ushort* a16_0 = (const ushort*)Av + (size_t)ra0 * K + scS;
  const ushort* a16_1 = (const ushort*)Av + (size_t)ra1 * K + scS;
  const ushort* bsrc[NCHB];
#pragma unroll
  for (int c = 0; c < NCHB; c++) {
    int rb = min(bn + 32 * c + srow, F - 1);
    bsrc[c] = BT + (size_t)rb * K + scS;
  }

  // direct-to-LDS staging: thread tid writes LDS bytes [tid*16) within each 4KB chunk
  // (wave-uniform base + lane*16); source col pre-swizzled so stored layout is swizzled.
  auto stage_lds = [&](int buf, int k0) {
#pragma unroll
    for (int c = 0; c < NCHB; c++)
      gload_lds16(bsrc[c] + k0, (char*)&Bs[buf][0] + c * 4096 + wv * 1024);
    if (!A_F32) {
      gload_lds16(a16_0 + k0, (char*)&As[buf][0] + wv * 1024);
      gload_lds16(a16_1 + k0, (char*)&As[buf][0] + 4096 + wv * 1024);
    }
  };
  auto stage_a32 = [&](int buf, const uint4& r00, const uint4& r01,
                       const uint4& r10, const uint4& r11) {
    union { uint4 u[2]; float4 f[2]; } c0; c0.u[0] = r00; c0.u[1] = r01;
    union { uint4 u[2]; float4 f[2]; } c1; c1.u[0] = r10; c1.u[1] = r11;
    union { short8 s; uint4 u; } o0; o0.s = cvt8(c0.f[0], c0.f[1]);
    union { short8 s; uint4 u; } o1; o1.s = cvt8(c1.f[0], c1.f[1]);
    *(uint4*)((char*)&As[buf][0] + srow * 128 + slotSwz * 16) = o0.u;        // rows 0..31
    *(uint4*)((char*)&As[buf][0] + (srow + 32) * 128 + slotSwz * 16) = o1.u; // rows 32..63
  };

  floatx4 acc[4][NJ] = {};

  // prologue: stage tile 0 into buffer 0
  stage_lds(0, 0);
  if (A_F32) {
    uint4 r00 = *(const uint4*)(a32_0);
    uint4 r01 = *(const uint4*)(a32_0 + 4);
    uint4 r10 = *(const uint4*)(a32_1);
    uint4 r11 = *(const uint4*)(a32_1 + 4);
    stage_a32(0, r00, r01, r10, r11);
  }
  __syncthreads();   // drains DMA (vmcnt 0 + lgkm 0): tile 0 ready

#pragma unroll
  for (int k0 = 0; k0 < K; k0 += 64) {
    const int cur = (k0 >> 6) & 1, nxt = cur ^ 1;   // compile-time (fully unrolled)
    const bool more = (k0 + 64 < K);
    uint4 r00, r01, r10, r11;
    if (more) {
      stage_lds(nxt, k0 + 64);          // DMA next tile; overlaps the MFMAs below
      if (A_F32) {
        r00 = *(const uint4*)(a32_0 + k0 + 64);
        r01 = *(const uint4*)(a32_0 + k0 + 68);
        r10 = *(const uint4*)(a32_1 + k0 + 64);
        r11 = *(const uint4*)(a32_1 + k0 + 68);
      }
    }

    // fragment reads (swizzled): row r, k-slice kk2 (0/1), quad q -> slot (kk2*4+q)^(ml&7)
    short8 af[2][4], bf[2][NJ];
#pragma unroll
    for (int kk2 = 0; kk2 < 2; kk2++) {
      const int slot = ((kk2 << 2) + q) ^ (ml & 7);
#pragma unroll
      for (int i = 0; i < 4; i++)
        af[kk2][i] = *(const short8*)((const char*)&As[cur][0] + (16 * i + ml) * 128 + slot * 16);
#pragma unroll
      for (int j = 0; j < NJ; j++)
        bf[kk2][j] = *(const short8*)((const char*)&Bs[cur][0] + (wn + 16 * j + ml) * 128 + slot * 16);
    }
#pragma unroll
    for (int kk2 = 0; kk2 < 2; kk2++)
#pragma unroll
      for (int i = 0; i < 4; i++)
#pragma unroll
        for (int j = 0; j < NJ; j++)
          acc[i][j] = __builtin_amdgcn_mfma_f32_16x16x32_bf16(af[kk2][i], bf[kk2][j], acc[i][j], 0, 0, 0);

    if (more) {
      if (A_F32) stage_a32(nxt, r00, r01, r10, r11);  // cvt+LDS write AFTER the MFMAs
      __syncthreads();                                // drains DMA + guards buffer swap
    }
  }

  if constexpr (LSM) {
    // fused log_softmax epilogue (F==NT==64): stash logits in LDS, reduce per row.
    __shared__ float lsm[64][65];   // stride 65: row-read conflict-free
#pragma unroll
    for (int i = 0; i < 4; i++)
#pragma unroll
      for (int rr = 0; rr < 4; rr++)
        lsm[16 * i + q * 4 + rr][wn + ml] = acc[i][0][rr] + bias[wn + ml];
    __syncthreads();
    for (int t = 0; t < 16; ++t) {          // wave wv owns rows wv*16 .. wv*16+15
      int r = (wv << 4) + t;
      float l = lsm[r][lane];
      float mx = l;
#pragma unroll
      for (int off = 32; off; off >>= 1) mx = fmaxf(mx, __shfl_xor(mx, off, 64));
      float e = __expf(l - mx);
#pragma unroll
      for (int off = 32; off; off >>= 1) e += __shfl_xor(e, off, 64);
      int m = bm + r;
      if (m < M) ((float*)Cv)[(size_t)m * 64 + lane] = (l - mx) - __logf(e);
    }
  } else {
    // epilogue: C/D col = lane&15, row = quad*4 + reg [m89 verified]
#pragma unroll
    for (int j = 0; j < NJ; j++) {
      int n = bn + wn + 16 * j + ml;
      float bv = bias ? bias[n] : 0.0f;
#pragma unroll
      for (int i = 0; i < 4; i++) {
#pragma unroll
        for (int rr = 0; rr < 4; rr++) {
          int m = bm + 16 * i + q * 4 + rr;
          if (m < M) {
            float val = acc[i][j][rr] + bv;
            if (OUT_F32) ((float*)Cv)[(size_t)m * F + n] = val;
            else         ((ushort*)Cv)[(size_t)m * F + n] = f2b(val);
          }
        }
      }
    }
  }
}

// ---------------- GCN aggregation: out[d] = relu(b + dinv_d^2*H[d] + sum_e w_e*H[s]) ----------
// One wave per destination node, split into two 32-lane halves: half h processes edges
// p0+h, p0+h+2, ... Each lane covers F/32 features -> 16 B (F=256) / 8 B (F=128) row loads.
// Edge weights come precomputed (f16 in edg high bits) -> no random dinv gather.
// Single clamped-index loop: every edge rides a 4-deep load pipeline (OOB slots: clamped
// valid index, weight 0). Halves merged with one __shfl_xor(32) per acc; half 0 stores.
template<int F>
__global__ __launch_bounds__(256) void agg_kernel(const ushort* __restrict__ H,
                                                  const float* __restrict__ bias,
                                                  const float* __restrict__ dinv,
                                                  const int* __restrict__ rp,
                                                  const unsigned* __restrict__ edg,
                                                  ushort* __restrict__ out, int n) {
  constexpr int VPL = F / 32;                      // 8 (F=256) or 4 (F=128)
  using hv_t = std::conditional_t<VPL == 8, uint4, uint2>;
  int wid = blockIdx.x * 4 + (threadIdx.x >> 6);
  if (wid >= n) return;
  const int lane = threadIdx.x & 63;
  const int half = lane >> 5;
  const int fo = (lane & 31) * VPL;
  const ushort* Hf = H + fo;

  float acc[VPL];
  if (half == 0) {                                 // bias + self-loop term on half 0 only
    float invd = dinv[wid], ws = invd * invd;
    hv_t h = *(const hv_t*)(Hf + (size_t)wid * F);
    if constexpr (VPL == 8) {
      acc[0] = bias[fo + 0] + ws * blo(h.x); acc[1] = bias[fo + 1] + ws * bhi(h.x);
      acc[2] = bias[fo + 2] + ws * blo(h.y); acc[3] = bias[fo + 3] + ws * bhi(h.y);
      acc[4] = bias[fo + 4] + ws * blo(h.z); acc[5] = bias[fo + 5] + ws * bhi(h.z);
      acc[6] = bias[fo + 6] + ws * blo(h.w); acc[7] = bias[fo + 7] + ws * bhi(h.w);
    } else {
      acc[0] = bias[fo + 0] + ws * blo(h.x); acc[1] = bias[fo + 1] + ws * bhi(h.x);
      acc[2] = bias[fo + 2] + ws * blo(h.y); acc[3] = bias[fo + 3] + ws * bhi(h.y);
    }
  } else {
#pragma unroll
    for (int v = 0; v < VPL; v++) acc[v] = 0.0f;
  }

  auto fmaU = [&](float w, const hv_t& h) {
    if constexpr (VPL == 8) {
      acc[0] += w * blo(h.x); acc[1] += w * bhi(h.x);
      acc[2] += w * blo(h.y); acc[3] += w * bhi(h.y);
      acc[4] += w * blo(h.z); acc[5] += w * bhi(h.z);
      acc[6] += w * blo(h.w); acc[7] += w * bhi(h.w);
    } else {
      acc[0] += w * blo(h.x); acc[1] += w * bhi(h.x);
      acc[2] += w * blo(h.y); acc[3] += w * bhi(h.y);
    }
  };

  const int p1 = rp[wid + 1];
  // clamped 4-deep pipeline: all edges of this half, 4 row-loads always in flight.
  for (int p = rp[wid] + half; p < p1; p += 8) {
    unsigned e[4]; float w[4];
#pragma unroll
    for (int u = 0; u < 4; u++) {
      int idx = p + 2 * u;
      bool ok = idx < p1;
      e[u] = edg[ok ? idx : (p1 - 1)];            // p1 >= 1 whenever the loop runs
      w[u] = ok ? __half2float(__ushort_as_half((ushort)(e[u] >> 16))) : 0.0f;
    }
    hv_t h[4];
#pragma unroll
    for (int u = 0; u < 4; u++)
      h[u] = *(const hv_t*)(Hf + (size_t)(e[u] & 0xffffu) * F);
#pragma unroll
    for (int u = 0; u < 4; u++) fmaU(w[u], h[u]);
  }

  // merge the two halves (both hold partial sums for the SAME features fo..fo+VPL)
#pragma unroll
  for (int v = 0; v < VPL; v++) acc[v] += __shfl_xor(acc[v], 32, 64);

  if (half == 0) {
    ushort* op = out + (size_t)wid * F + fo;
    if constexpr (VPL == 8) {
      float4 lo = {fmaxf(acc[0], 0.0f), fmaxf(acc[1], 0.0f), fmaxf(acc[2], 0.0f), fmaxf(acc[3], 0.0f)};
      float4 hi = {fmaxf(acc[4], 0.0f), fmaxf(acc[5], 0.0f), fmaxf(acc[6], 0.0f), fmaxf(acc[7], 0.0f)};
      union { short8 s; uint4 u; } o; o.s = cvt8(lo, hi);
      *(uint4*)op = o.u;
    } else {
      union { __hip_bfloat162 h[2]; uint2 u; } o;
      o.h[0] = __float22bfloat162_rn({fmaxf(acc[0], 0.0f), fmaxf(acc[1], 0.0f)});
      o.h[1] = __float22bfloat162_rn({fmaxf(acc[2], 0.0f), fmaxf(acc[3], 0.0f)});
      *(uint2*)op = o.u;
    }
  }
}

// ---------------- launch ----------------

extern "C" void kernel_launch(void* const* d_in, const int* in_sizes, int n_in,
                              void* d_out, int out_size, void* d_ws, size_t ws_size,
                              hipStream_t stream) {
  const float* x  = (const float*)d_in[0];   // f32 per reference dtypes
  const int* ei   = (const int*)d_in[1];
  const float* W1 = (const float*)d_in[2];
  const float* b1 = (const float*)d_in[3];
  const float* W2 = (const float*)d_in[4];
  const float* b2 = (const float*)d_in[5];
  const float* Wc = (const float*)d_in[6];
  const float* bc = (const float*)d_in[7];

  const int N = in_sizes[0] / F_IN;
  const int E = in_sizes[1] / 2;
  const int* e_src = ei;
  const int* e_dst = ei + E;

  // workspace layout (256B aligned slices); total ~55.3 MB
  char* ws = (char*)d_ws;
  size_t off = 0;
  auto alloc = [&](size_t bytes) { char* p = ws + off; off += (bytes + 255) & ~(size_t)255; return p; };
  int*      cnt  = (int*)alloc((size_t)N * 4);
  float*    dinv = (float*)alloc((size_t)N * 4);
  int*      rp   = (int*)alloc((size_t)(N + 1) * 4);
  int*      part = (int*)alloc((size_t)1024 * 4);
  unsigned* edg  = (unsigned*)alloc((size_t)E * 4);
  ushort*   w1t  = (ushort*)alloc((size_t)F_HID * F_IN * 2);
  ushort*   w2t  = (ushort*)alloc((size_t)F_MID * F_HID * 2);
  ushort*   wct  = (ushort*)alloc((size_t)F_OUT * F_MID * 2);
  ushort*   bufH = (ushort*)alloc((size_t)N * F_HID * 2);  // pre-agg H (layer1: N x 256 bf16)
  ushort*   bufG = (ushort*)alloc((size_t)N * F_HID * 2);  // post-agg h
  (void)ws_size; (void)n_in; (void)out_size;

  int gE = (E + 255) / 256, gW = (N + 3) / 4;
  int gM64 = (N + 63) / 64;
  int nb = (N + 1023) / 1024;

  // CSR + dinv (dinv fused into scan1)
  hipMemsetAsync(cnt, 0, (size_t)N * 4, stream);
  hist_kernel<<<gE, 256, 0, stream>>>(e_dst, cnt, E);
  scan1_kernel<<<nb, 1024, 0, stream>>>(cnt, rp, part, dinv, N);
  scan2_kernel<<<1, 1024, 0, stream>>>(part, rp, nb, N);
  scan3_kernel<<<nb, 1024, 0, stream>>>(part, rp, N);
  fill_kernel<<<gE, 256, 0, stream>>>(e_src, e_dst, rp, cnt, dinv, edg, E);

  // weight transposes (f32 -> bf16 B^T layout)
  transpose_kernel<<<(F_IN * F_HID + 255) / 256, 256, 0, stream>>>(W1, w1t, F_IN, F_HID);
  transpose_kernel<<<(F_HID * F_MID + 255) / 256, 256, 0, stream>>>(W2, w2t, F_HID, F_MID);
  transpose_kernel<<<(F_MID * F_OUT + 255) / 256, 256, 0, stream>>>(Wc, wct, F_MID, F_OUT);

  // layer 1: H = x @ W1 (f32 A, 64x128 tiles x 2 col-tiles, BK=64, XCD pair swizzle)
  gemm64db<512, 128, true, false, false, true><<<dim3(gM64, 2), 256, 0, stream>>>(x, w1t, nullptr, bufH, N, F_HID);
  agg_kernel<F_HID><<<gW, 256, 0, stream>>>(bufH, b1, dinv, rp, edg, bufG, N);

  // layer 2: H2 = h1 @ W2 (64x128 tiles, BK=64)
  gemm64db<256, 128, false, false, false, false><<<dim3(gM64, 1), 256, 0, stream>>>(bufG, w2t, nullptr, bufH, N, F_MID);
  agg_kernel<F_MID><<<gW, 256, 0, stream>>>(bufH, b2, dinv, rp, edg, bufG, N);

  // classifier + fused log_softmax: d_out = log_softmax(h2 @ Wc + bc), no logits round-trip
  gemm64db<128, 64, false, true, true, false><<<dim3(gM64, 1), 256, 0, stream>>>(bufG, wct, bc, d_out, N, F_OUT);
}